// Round 8
// baseline (92.567 us; speedup 1.0000x reference)
//
#include <hip/hip_runtime.h>

#define BEVN 100
#define NB 8
#define NC 512
#define FH 88
#define FW 176
#define HWSZ (FH * FW)          // 15488 pixels per channel slice
#define NG4  (HWSZ / 4)         // 3872 uint4 groups per packed 2-channel buffer
#define G4PR (FW / 4)           // 44 groups per image row
#define NPAIR (BEVN * BEVN / 2) // 5000 cell-pairs
#define NTASK 8                 // channel-pair tasks per block
#define NBLK (NB * NC / 2 / NTASK) // 256 blocks (1 per CU)
#define NCONS 768               // consumer threads (12 waves)
#define NPROD 256               // producer threads (4 waves)

typedef float    f32x4 __attribute__((ext_vector_type(4)));
typedef float    f32x2 __attribute__((ext_vector_type(2)));
typedef unsigned u32x4 __attribute__((ext_vector_type(4)));

// Producer/consumer wave specialization: 1 block/CU, 8 channel-pair tasks.
// Waves 12-15 stage task t+1 (marked image rows only, bf16 2-ch packed) into
// the spare LDS buffer while waves 0-11 compute task t -> HBM read stream
// overlaps compute+writes continuously; one barrier per task.
__device__ __forceinline__ unsigned bf16rne(float f) {
    const unsigned b = __float_as_uint(f);
    return (b + 0x7fffu + ((b >> 16) & 1u)) >> 16;   // round-nearest-even
}
__device__ __forceinline__ float lo16f(unsigned u) { return __uint_as_float(u << 16); }
__device__ __forceinline__ float hi16f(unsigned u) { return __uint_as_float(u & 0xffff0000u); }

__global__ __launch_bounds__(1024, 4)
void vt_kernel(const float* __restrict__ img,
               const float* __restrict__ intr,
               const int* __restrict__ p_imw,
               const int* __restrict__ p_imh,
               float* __restrict__ out)
{
    __shared__ unsigned      buf[2][HWSZ];   // 2 x 61,952 B packed {bf16 c0 | bf16 c1<<16}
    __shared__ float4        ytab[BEVN * 3]; // {wy0/3, wy1/3, rowbase0, rowbase1}
    __shared__ unsigned char marked[FH];
    __shared__ short         mlist[FH];      // compacted marked-row list
    __shared__ int           nm_sh;

    const int blk = blockIdx.x;          // [0, 256)
    const int b   = blk >> 5;            // 32 blocks per batch
    const int grp = blk & 31;            // pair-group: tasks cp = grp*8 + t
    const int tid = (int)threadIdx.x;

    const float fx  = intr[b * 9 + 0];
    const float cxv = intr[b * 9 + 2];
    const float fy  = intr[b * 9 + 4];
    const float cyv = intr[b * 9 + 5];
    const float wsc = (float)FW / (float)p_imw[0];   // 0.25
    const float hsc = (float)FH / (float)p_imh[0];   // 0.25

    if (tid < FH) marked[tid] = 0;
    __syncthreads();

    // ---- ytab + row marking (same arithmetic -> provably consistent) ----
    if (tid < BEVN * 3) {
        const int   i  = tid / 3;
        const int   k  = tid - 3 * i;
        const float z  = 0.125f + 0.5f * (float)i;
        const float iz = 1.0f / z;
        const float yk = (k == 0) ? -1.0f : ((k == 1) ? 0.5f : 2.0f);
        const float yp = fmaf(fy * yk * iz + cyv, hsc, -0.5f);
        const float yf = floorf(yp);
        const int   y0 = (int)yf;
        float wy1 = yp - yf;
        float wy0 = 1.0f - wy1;
        wy0 = ((unsigned)y0 < (unsigned)FH) ? wy0 : 0.0f;
        wy1 = ((unsigned)(y0 + 1) < (unsigned)FH) ? wy1 : 0.0f;
        if (wy0 != 0.0f) marked[y0] = 1;
        if (wy1 != 0.0f) marked[y0 + 1] = 1;
        const int yb0 = min(max(y0, 0), FH - 1) * FW;
        const int yb1 = min(max(y0 + 1, 0), FH - 1) * FW;
        float4 e;
        e.x = wy0 * (1.0f / 3.0f);
        e.y = wy1 * (1.0f / 3.0f);
        e.z = __int_as_float(yb0);
        e.w = __int_as_float(yb1);
        ytab[tid] = e;
    }
    __syncthreads();

    if (tid == 0) {                      // compact marked-row list
        int n = 0;
        for (int r = 0; r < FH; ++r) if (marked[r]) mlist[n++] = (short)r;
        nm_sh = n;
    }
    // zero-fill BOTH buffers (unmarked rows stay zero across all tasks)
    {
        const u32x4 zz = {0u, 0u, 0u, 0u};
        u32x4* l0 = (u32x4*)buf[0];
        u32x4* l1 = (u32x4*)buf[1];
        #pragma unroll
        for (int q = 0; q < 4; ++q) {
            const int g = tid + q * 1024;
            if (g < NG4) { l0[g] = zz; l1[g] = zz; }
        }
    }
    __syncthreads();
    const int nm = nm_sh;
    const int ng = nm * G4PR;            // marked groups per channel

    // staging helper: threads [base0, base0+stride) fill dst from task cp
    auto stage = [&](unsigned* dst, int cp, int base0, int stride) {
        const int bc0 = b * NC + 2 * cp;
        const f32x4* __restrict__ s0 = (const f32x4*)(img + (size_t)bc0 * HWSZ);
        const f32x4* __restrict__ s1 = s0 + NG4;
        u32x4* l4 = (u32x4*)dst;
        #pragma unroll 4
        for (int idx = base0; idx < ng; idx += stride) {
            const int r = idx / G4PR;
            const int c = idx - r * G4PR;
            const int g = (int)mlist[r] * G4PR + c;
            const f32x4 a  = __builtin_nontemporal_load(s0 + g);
            const f32x4 bb = __builtin_nontemporal_load(s1 + g);
            u32x4 u;
            u.x = bf16rne(a.x) | (bf16rne(bb.x) << 16);
            u.y = bf16rne(a.y) | (bf16rne(bb.y) << 16);
            u.z = bf16rne(a.z) | (bf16rne(bb.z) << 16);
            u.w = bf16rne(a.w) | (bf16rne(bb.w) << 16);
            l4[g] = u;
        }
    };

    // x-projection: xpix = a_j * invz + bx
    const float axs = 0.5f * fx * wsc;
    const float axb = -24.875f * fx * wsc;
    const float bx  = fmaf(cxv, wsc, -0.5f);

    // ---- prologue: all threads stage task 0 into buf[0] ----
    stage(buf[0], grp * NTASK, tid, 1024);
    __syncthreads();

    for (int t = 0; t < NTASK; ++t) {
        if (tid >= NCONS) {
            // -------- producers: stage next task into spare buffer --------
            if (t + 1 < NTASK)
                stage(buf[(t + 1) & 1], grp * NTASK + t + 1, tid - NCONS, NPROD);
        } else {
            // -------- consumers: compute current task --------
            const unsigned* __restrict__ cb = buf[t & 1];
            const int bc0 = b * NC + 2 * (grp * NTASK + t);
            float* __restrict__ op0 = out + (size_t)bc0 * (BEVN * BEVN);
            float* __restrict__ op1 = op0 + (BEVN * BEVN);

            for (int p = tid; p < NPAIR; p += NCONS) {
                const int i  = p / 50;
                const int jp = p - 50 * i;
                const float z    = fmaf(0.5f, (float)i, 0.125f);
                const float invz = __builtin_amdgcn_rcpf(z);

                int   xb[2];
                float w0[2], w1[2];
                #pragma unroll
                for (int e = 0; e < 2; ++e) {
                    const float aj   = fmaf((float)(2 * jp + e), axs, axb);
                    const float xpix = fmaf(aj, invz, bx);
                    const float f    = floorf(xpix);
                    const int   x0   = (int)f;
                    float wx1 = xpix - f;
                    float wx0 = 1.0f - wx1;
                    wx0 = ((unsigned)x0 < (unsigned)FW) ? wx0 : 0.0f;
                    wx1 = ((unsigned)(x0 + 1) < (unsigned)FW) ? wx1 : 0.0f;
                    const int xbe = min(max(x0, 0), FW - 2);
                    const int d   = x0 - xbe;
                    w0[e] = (d == 0) ? wx0 : ((d < 0) ? wx1 : 0.0f);
                    w1[e] = (d == 0) ? wx1 : ((d < 0) ? 0.0f : wx0);
                    xb[e] = xbe;
                }

                f32x2 rA, rB;
                const float wsum = (w0[0] + w1[0]) + (w0[1] + w1[1]);
                if (wsum == 0.0f) {
                    rA = (f32x2){0.0f, 0.0f};
                    rB = (f32x2){0.0f, 0.0f};
                } else {
                    float accA[2] = {0.0f, 0.0f};
                    float accB[2] = {0.0f, 0.0f};
                    #pragma unroll
                    for (int k = 0; k < 3; ++k) {
                        const float4 e4  = ytab[i * 3 + k];
                        const int    yb0 = __float_as_int(e4.z);
                        const int    yb1 = __float_as_int(e4.w);
                        #pragma unroll
                        for (int e = 0; e < 2; ++e) {
                            const unsigned* r0 = cb + (yb0 + xb[e]);
                            const unsigned* r1 = cb + (yb1 + xb[e]);
                            const unsigned u00 = r0[0], u01 = r0[1];   // ds_read2_b32
                            const unsigned u10 = r1[0], u11 = r1[1];   // ds_read2_b32
                            const float h0a = fmaf(w1[e], lo16f(u01), w0[e] * lo16f(u00));
                            const float h1a = fmaf(w1[e], lo16f(u11), w0[e] * lo16f(u10));
                            accA[e] = fmaf(e4.x, h0a, accA[e]);
                            accA[e] = fmaf(e4.y, h1a, accA[e]);
                            const float h0b = fmaf(w1[e], hi16f(u01), w0[e] * hi16f(u00));
                            const float h1b = fmaf(w1[e], hi16f(u11), w0[e] * hi16f(u10));
                            accB[e] = fmaf(e4.x, h0b, accB[e]);
                            accB[e] = fmaf(e4.y, h1b, accB[e]);
                        }
                    }
                    rA = (f32x2){accA[0], accA[1]};
                    rB = (f32x2){accB[0], accB[1]};
                }
                __builtin_nontemporal_store(rA, (f32x2*)(op0 + 2 * p));
                __builtin_nontemporal_store(rB, (f32x2*)(op1 + 2 * p));
            }
        }
        __syncthreads();   // task boundary: next buffer ready, current free
    }
}

extern "C" void kernel_launch(void* const* d_in, const int* in_sizes, int n_in,
                              void* d_out, int out_size, void* d_ws, size_t ws_size,
                              hipStream_t stream) {
    const float* img  = (const float*)d_in[0];
    const float* intr = (const float*)d_in[1];
    const int*   imw  = (const int*)d_in[2];
    const int*   imh  = (const int*)d_in[3];
    float*       out  = (float*)d_out;

    dim3 grid(NBLK);     // 256 blocks, 1 per CU
    dim3 block(1024);
    hipLaunchKernelGGL(vt_kernel, grid, block, 0, stream,
                       img, intr, imw, imh, out);
}